// Round 8
// baseline (241.987 us; speedup 1.0000x reference)
//
#include <hip/hip_runtime.h>
#include <hip/hip_bf16.h>
#include <math.h>

#define N_NODES 50000
#define F_IN 128
#define HC 128
#define N_EDGES 800000
#define E_HALF_R (N_EDGES / 2)      // 400000 (real edges only; self-loops via init_k)
#define NEG_SLOPE 0.2f
#define GN_EPS 1e-5f
#define DEG_STRIDE 16               // one counter per 64B line
#define CAP 64                      // padded CSR capacity (max deg ~35 + self)
#define GB ((N_NODES + 127) / 128)  // 391 gemm-role blocks
#define EBR ((E_HALF_R + 511) / 512) // 782 edge-role blocks (2 edges/thread)
#define FUSED_GRID (GB + EBR)       // 1173 == 3*GB exactly
#define ST_BLOCKS 256               // x16 row-lanes = 4096 slots, 13 unrolled steps
#define ST_ITERS 13                 // 4096*13 = 53248 >= 50000
#define NM_BLOCKS 1024              // x8 row-lanes = 8192 slots, 7 unrolled steps
#define NM_ITERS 7                  // 8192*7 = 57344 >= 50000

typedef __attribute__((ext_vector_type(8))) short short8;
typedef __attribute__((ext_vector_type(4))) float floatx4;

__device__ inline ushort f2bf(float f) {
    unsigned u = __float_as_uint(f);
    u += 0x7FFF + ((u >> 16) & 1);   // RNE (inputs are finite/bounded)
    return (ushort)(u >> 16);
}

// ---------------------------------------------------------------- init: W transpose + self-loop CSR slot0 + stats zero
__global__ __launch_bounds__(256) void init_k(const float* __restrict__ Wl,
                                              const float* __restrict__ Wr,
                                              ushort* __restrict__ wtl,
                                              ushort* __restrict__ wtr,
                                              int* __restrict__ deg16,
                                              ushort* __restrict__ csrp,
                                              float* __restrict__ gsum) {
    int gid = blockIdx.x * 256 + threadIdx.x;
    if (gid < 16384) {               // W is [k][n]; write [n][k] bf16
        int k = gid >> 7, n = gid & 127;
        wtl[n * 128 + k] = f2bf(Wl[gid]);
        wtr[n * 128 + k] = f2bf(Wr[gid]);
    }
    if (gid < 256) gsum[gid] = 0.f;  // gsum[128] + gsumsq[128] contiguous
    if (gid < N_NODES) {
        deg16[gid * DEG_STRIDE] = 1;         // slot 0 taken by self-loop
        csrp[(size_t)gid * CAP] = (ushort)gid;
    }
}

// ---------------------------------------------------------------- fused edge-scatter + dual MFMA GEMM
// Role-split blocks: bi%3==1 -> GEMM (391), else edge (782). Edge blocks are
// atomic-latency-bound (15.1 G returning-atomics/s fabric ceiling, invariant
// R0-R6 across occupancy 30-57%); GEMM blocks backfill the idle pipes.
__global__ __launch_bounds__(512) void eg_k(const int* __restrict__ ei,
                                            int* __restrict__ deg16,
                                            ushort* __restrict__ csrp,
                                            const float* __restrict__ x,
                                            const ushort* __restrict__ wtl,
                                            const ushort* __restrict__ wtr,
                                            ushort* __restrict__ xlb,
                                            ushort* __restrict__ xrb) {
    __shared__ ushort Wt[2][128][136];
    const int bi = blockIdx.x;
    const int tid = threadIdx.x;
    const bool isG = (bi % 3 == 1);

    if (!isG) {
        // ---- edge role: 2 independent real edges per thread (split halves) ----
        const int eb = bi - (bi + 1) / 3;
        int gid = eb * 512 + tid;
        if (gid >= E_HALF_R) return;
        {   // edge A: [0, 400000)
            int src = ei[gid], dst = ei[N_EDGES + gid];
            int r = atomicAdd(&deg16[dst * DEG_STRIDE], 1);
            if (r < CAP) csrp[(size_t)dst * CAP + r] = (ushort)src;
        }
        {   // edge B: [400000, 800000)
            int e = gid + E_HALF_R;
            int src = ei[e], dst = ei[N_EDGES + e];
            int r = atomicAdd(&deg16[dst * DEG_STRIDE], 1);
            if (r < CAP) csrp[(size_t)dst * CAP + r] = (ushort)src;
        }
        return;
    }

    // ---- gemm role: 8 waves, 128 rows/block, LDS-staged both W ----
    const int gb = bi / 3;
#pragma unroll
    for (int i = 0; i < 4; ++i) {
        int idx = i * 512 + tid;
        int n = idx >> 4, k8 = (idx & 15) * 8;
        *(int4*)&Wt[0][n][k8] = *(const int4*)(wtl + n * 128 + k8);
        *(int4*)&Wt[1][n][k8] = *(const int4*)(wtr + n * 128 + k8);
    }
    __syncthreads();

    const int w = tid >> 6, lane = tid & 63;
    const int quad = lane >> 4, l16 = lane & 15;
    const int rbase = gb * 128 + w * 16;
    const int grow = rbase + l16;
    const float* ap = x + (size_t)(grow < N_NODES ? grow : (N_NODES - 1)) * F_IN + quad * 8;

    floatx4 accL[8], accR[8];
#pragma unroll
    for (int nt = 0; nt < 8; ++nt) {
        accL[nt] = (floatx4){0.f, 0.f, 0.f, 0.f};
        accR[nt] = (floatx4){0.f, 0.f, 0.f, 0.f};
    }

#pragma unroll
    for (int ks = 0; ks < 4; ++ks) {
        float4 a0 = *(const float4*)(ap + ks * 32 + 0);
        float4 a1 = *(const float4*)(ap + ks * 32 + 4);
        short8 af;
        af[0] = (short)f2bf(a0.x); af[1] = (short)f2bf(a0.y);
        af[2] = (short)f2bf(a0.z); af[3] = (short)f2bf(a0.w);
        af[4] = (short)f2bf(a1.x); af[5] = (short)f2bf(a1.y);
        af[6] = (short)f2bf(a1.z); af[7] = (short)f2bf(a1.w);
#pragma unroll
        for (int nt = 0; nt < 8; ++nt) {
            short8 bfl = *(const short8*)&Wt[0][nt * 16 + l16][ks * 32 + quad * 8];
            short8 bfr = *(const short8*)&Wt[1][nt * 16 + l16][ks * 32 + quad * 8];
            accL[nt] = __builtin_amdgcn_mfma_f32_16x16x32_bf16(af, bfl, accL[nt], 0, 0, 0);
            accR[nt] = __builtin_amdgcn_mfma_f32_16x16x32_bf16(af, bfr, accR[nt], 0, 0, 0);
        }
    }
    // C/D: row = rbase + quad*4 + r, col = nt*16 + l16
#pragma unroll
    for (int r = 0; r < 4; ++r) {
        int gro = rbase + quad * 4 + r;
        if (gro < N_NODES) {
            ushort* opl = xlb + (size_t)gro * HC + l16;
            ushort* opr = xrb + (size_t)gro * HC + l16;
#pragma unroll
            for (int nt = 0; nt < 8; ++nt) {
                opl[nt * 16] = f2bf(accL[nt][r]);
                opr[nt * 16] = f2bf(accR[nt][r]);
            }
        }
    }
}

// ---------------------------------------------------------------- fused attention — batched-gather (latency fix)
// One wave per dst. LATENCY FIX: the whole row's gathers are issued up front
// in wave-uniform buckets of {4, 8, 8+8} steps (clamped to self-loop slot 0,
// which is cache-hot) -> 4-8 independent gathers in flight vs 2 before.
// Consumption stays in ascending slot order: accumulation bitwise-identical.
__global__ __launch_bounds__(256) void attn_k(const ushort* __restrict__ xlb,
                                              const ushort* __restrict__ xrb,
                                              const int* __restrict__ deg16,
                                              const ushort* __restrict__ csrp,
                                              const float* __restrict__ att,
                                              const float* __restrict__ bias,
                                              float* __restrict__ out) {
    const int wid = threadIdx.x >> 6, lane = threadIdx.x & 63;
    const int dst = blockIdx.x * 4 + wid;
    if (dst >= N_NODES) return;
    const int e = lane >> 4, s = lane & 15;
    float xrv[8], av[8];
    {
        int4 xv = *(const int4*)(xrb + (size_t)dst * HC + s * 8);
        xrv[0] = __uint_as_float(((unsigned)xv.x) << 16);
        xrv[1] = __uint_as_float(((unsigned)xv.x) & 0xffff0000u);
        xrv[2] = __uint_as_float(((unsigned)xv.y) << 16);
        xrv[3] = __uint_as_float(((unsigned)xv.y) & 0xffff0000u);
        xrv[4] = __uint_as_float(((unsigned)xv.z) << 16);
        xrv[5] = __uint_as_float(((unsigned)xv.z) & 0xffff0000u);
        xrv[6] = __uint_as_float(((unsigned)xv.w) << 16);
        xrv[7] = __uint_as_float(((unsigned)xv.w) & 0xffff0000u);
        float4 a0 = *(const float4*)(att + s * 8);
        float4 a1 = *(const float4*)(att + s * 8 + 4);
        av[0] = a0.x; av[1] = a0.y; av[2] = a0.z; av[3] = a0.w;
        av[4] = a1.x; av[5] = a1.y; av[6] = a1.z; av[7] = a1.w;
    }
    float l = 0.f;
    float acc[8] = {0.f, 0.f, 0.f, 0.f, 0.f, 0.f, 0.f, 0.f};
    const int nk = min(deg16[dst * DEG_STRIDE], CAP);
    const int sv = (int)csrp[(size_t)dst * CAP + lane];   // lanes >= nk never selected

#define EDGE_STEP(rv, valid)                                                   \
    {                                                                          \
        float f0 = __uint_as_float(((unsigned)(rv).x) << 16);                  \
        float f1 = __uint_as_float(((unsigned)(rv).x) & 0xffff0000u);          \
        float f2 = __uint_as_float(((unsigned)(rv).y) << 16);                  \
        float f3 = __uint_as_float(((unsigned)(rv).y) & 0xffff0000u);          \
        float f4 = __uint_as_float(((unsigned)(rv).z) << 16);                  \
        float f5 = __uint_as_float(((unsigned)(rv).z) & 0xffff0000u);          \
        float f6 = __uint_as_float(((unsigned)(rv).w) << 16);                  \
        float f7 = __uint_as_float(((unsigned)(rv).w) & 0xffff0000u);          \
        float t_, part_;                                                       \
        t_ = f0 + xrv[0]; t_ = t_ > 0.f ? t_ : NEG_SLOPE * t_; part_ = av[0] * t_;  \
        t_ = f1 + xrv[1]; t_ = t_ > 0.f ? t_ : NEG_SLOPE * t_; part_ += av[1] * t_; \
        t_ = f2 + xrv[2]; t_ = t_ > 0.f ? t_ : NEG_SLOPE * t_; part_ += av[2] * t_; \
        t_ = f3 + xrv[3]; t_ = t_ > 0.f ? t_ : NEG_SLOPE * t_; part_ += av[3] * t_; \
        t_ = f4 + xrv[4]; t_ = t_ > 0.f ? t_ : NEG_SLOPE * t_; part_ += av[4] * t_; \
        t_ = f5 + xrv[5]; t_ = t_ > 0.f ? t_ : NEG_SLOPE * t_; part_ += av[5] * t_; \
        t_ = f6 + xrv[6]; t_ = t_ > 0.f ? t_ : NEG_SLOPE * t_; part_ += av[6] * t_; \
        t_ = f7 + xrv[7]; t_ = t_ > 0.f ? t_ : NEG_SLOPE * t_; part_ += av[7] * t_; \
        part_ += __shfl_xor(part_, 1, 4);                                      \
        part_ += __shfl_xor(part_, 2, 4);                                      \
        float p = (valid) ? __expf(part_) : 0.f;                               \
        l += p;                                                                \
        acc[0] += p * f0; acc[1] += p * f1; acc[2] += p * f2; acc[3] += p * f3;\
        acc[4] += p * f4; acc[5] += p * f5; acc[6] += p * f6; acc[7] += p * f7;\
    }

#define GATHER(dst_rv, step)                                                   \
    {                                                                          \
        int idx_ = (step) * 4 + e;                                             \
        int ii_ = idx_ < nk ? idx_ : 0;                                        \
        int sr_ = __shfl(sv, ii_, 64);                                         \
        (dst_rv) = *(const int4*)(xlb + (size_t)sr_ * HC + s * 8);             \
    }

    const int nsteps = (nk + 3) >> 2;   // 1..16 steps of 4 edges (nk>=1)
    int4 rv[8];
    if (nsteps <= 4) {                  // nk <= 16: ~47% of dsts
        GATHER(rv[0], 0) GATHER(rv[1], 1) GATHER(rv[2], 2) GATHER(rv[3], 3)
        EDGE_STEP(rv[0], (0 + e) < nk)
        EDGE_STEP(rv[1], (4 + e) < nk)
        EDGE_STEP(rv[2], (8 + e) < nk)
        EDGE_STEP(rv[3], (12 + e) < nk)
    } else if (nsteps <= 8) {           // nk <= 32: ~all the rest
#pragma unroll
        for (int u = 0; u < 8; ++u) GATHER(rv[u], u)
#pragma unroll
        for (int u = 0; u < 8; ++u) EDGE_STEP(rv[u], (u * 4 + e) < nk)
    } else {                            // nk <= 64: rare tail
#pragma unroll
        for (int u = 0; u < 8; ++u) GATHER(rv[u], u)
#pragma unroll
        for (int u = 0; u < 8; ++u) EDGE_STEP(rv[u], true)
#pragma unroll
        for (int u = 0; u < 8; ++u) GATHER(rv[u], u + 8)
#pragma unroll
        for (int u = 0; u < 8; ++u) EDGE_STEP(rv[u], ((u + 8) * 4 + e) < nk)
    }
#undef GATHER
#undef EDGE_STEP

    l += __shfl_xor(l, 16, 64);
    l += __shfl_xor(l, 32, 64);
#pragma unroll
    for (int c = 0; c < 8; ++c) {
        acc[c] += __shfl_xor(acc[c], 16, 64);
        acc[c] += __shfl_xor(acc[c], 32, 64);
    }
    if (e == 0) {
        float inv = 1.0f / l;
        float4 b0 = *(const float4*)(bias + s * 8);
        float4 b1 = *(const float4*)(bias + s * 8 + 4);
        float4 o0 = make_float4(acc[0] * inv + b0.x, acc[1] * inv + b0.y,
                                acc[2] * inv + b0.z, acc[3] * inv + b0.w);
        float4 o1 = make_float4(acc[4] * inv + b1.x, acc[5] * inv + b1.y,
                                acc[6] * inv + b1.z, acc[7] * inv + b1.w);
        *(float4*)(out + (size_t)dst * HC + s * 8)     = o0;
        *(float4*)(out + (size_t)dst * HC + s * 8 + 4) = o1;
    }
}

// ---------------------------------------------------------------- per-feature sum/sumsq (13 independent loads in flight)
__global__ __launch_bounds__(512) void stats_k(const float* __restrict__ out,
                                               float* __restrict__ gsum,
                                               float* __restrict__ gsumsq) {
    const int t = threadIdx.x;
    const int fg = t & 31;          // features 4fg..4fg+3
    const int rl = t >> 5;          // 0..15 row-lane
    const int rbase = blockIdx.x * 16 + rl;
    float4 v[ST_ITERS];
#pragma unroll
    for (int i = 0; i < ST_ITERS; ++i) {
        int r = rbase + i * (ST_BLOCKS * 16);
        int rr = r < N_NODES ? r : 0;            // clamp addr, mask below
        v[i] = *(const float4*)(out + (size_t)rr * HC + fg * 4);
    }
    float4 s  = make_float4(0.f, 0.f, 0.f, 0.f);
    float4 s2 = make_float4(0.f, 0.f, 0.f, 0.f);
#pragma unroll
    for (int i = 0; i < ST_ITERS; ++i) {
        int r = rbase + i * (ST_BLOCKS * 16);
        if (r < N_NODES) {
            s.x += v[i].x; s.y += v[i].y; s.z += v[i].z; s.w += v[i].w;
            s2.x += v[i].x * v[i].x; s2.y += v[i].y * v[i].y;
            s2.z += v[i].z * v[i].z; s2.w += v[i].w * v[i].w;
        }
    }
    __shared__ float4 L1[512], L2[512];
    L1[t] = s; L2[t] = s2;
    __syncthreads();
#pragma unroll
    for (int off = 256; off >= 32; off >>= 1) {
        if (t < off) {
            float4 a = L1[t], b = L1[t + off];
            a.x += b.x; a.y += b.y; a.z += b.z; a.w += b.w; L1[t] = a;
            float4 c = L2[t], d = L2[t + off];
            c.x += d.x; c.y += d.y; c.z += d.z; c.w += d.w; L2[t] = c;
        }
        __syncthreads();
    }
    if (t < 32) {
        float4 a = L1[t], c = L2[t];
        atomicAdd(&gsum[t * 4 + 0], a.x); atomicAdd(&gsum[t * 4 + 1], a.y);
        atomicAdd(&gsum[t * 4 + 2], a.z); atomicAdd(&gsum[t * 4 + 3], a.w);
        atomicAdd(&gsumsq[t * 4 + 0], c.x); atomicAdd(&gsumsq[t * 4 + 1], c.y);
        atomicAdd(&gsumsq[t * 4 + 2], c.z); atomicAdd(&gsumsq[t * 4 + 3], c.w);
    }
}

// ---------------------------------------------------------------- GraphNorm finalize (7 independent loads in flight)
__global__ __launch_bounds__(256) void norm_k(float* __restrict__ out,
                                              const float* __restrict__ gsum,
                                              const float* __restrict__ gsumsq,
                                              const float* __restrict__ gw,
                                              const float* __restrict__ gb,
                                              const float* __restrict__ gms) {
    const int t = threadIdx.x;
    const int fg = t & 31;          // features 4fg..4fg+3
    const int rl = t >> 5;          // 0..7
    const int rbase = blockIdx.x * 8 + rl;
    float4 v[NM_ITERS];
#pragma unroll
    for (int i = 0; i < NM_ITERS; ++i) {
        int r = rbase + i * (NM_BLOCKS * 8);
        int rr = r < N_NODES ? r : 0;
        v[i] = *(const float4*)(out + (size_t)rr * HC + fg * 4);
    }
    const float invN = 1.0f / (float)N_NODES;
    float4 sm = *(const float4*)(gsum + fg * 4);
    float4 sq = *(const float4*)(gsumsq + fg * 4);
    float4 gv = *(const float4*)(gms + fg * 4);
    float4 wv = *(const float4*)(gw + fg * 4);
    float4 bv = *(const float4*)(gb + fg * 4);
    float4 a, b;
#define MKAB(c)                                                                \
    {                                                                          \
        float mean = sm.c * invN, msq = sq.c * invN, g = gv.c;                 \
        float var = msq - 2.f * g * mean * mean + g * g * mean * mean;         \
        a.c = wv.c * rsqrtf(var + GN_EPS);                                     \
        b.c = bv.c - a.c * g * mean;                                           \
    }
    MKAB(x) MKAB(y) MKAB(z) MKAB(w)
#undef MKAB
#pragma unroll
    for (int i = 0; i < NM_ITERS; ++i) {
        int r = rbase + i * (NM_BLOCKS * 8);
        if (r < N_NODES) {
            float4 w = v[i];
            w.x = a.x * w.x + b.x; w.y = a.y * w.y + b.y;
            w.z = a.z * w.z + b.z; w.w = a.w * w.w + b.w;
            *(float4*)(out + (size_t)r * HC + fg * 4) = w;
        }
    }
}

// ---------------------------------------------------------------- launch
extern "C" void kernel_launch(void* const* d_in, const int* in_sizes, int n_in,
                              void* d_out, int out_size, void* d_ws, size_t ws_size,
                              hipStream_t stream) {
    const float* x    = (const float*)d_in[0];
    const int*   ei   = (const int*)d_in[1];
    const float* Wl   = (const float*)d_in[2];
    const float* Wr   = (const float*)d_in[3];
    const float* att  = (const float*)d_in[4];
    const float* bias = (const float*)d_in[5];
    const float* gw   = (const float*)d_in[6];
    const float* gb   = (const float*)d_in[7];
    const float* gms  = (const float*)d_in[8];
    float* out = (float*)d_out;

    // workspace layout (~35.3 MB), all segments 16B-aligned
    ushort* xlb   = (ushort*)d_ws;                          // 12.8 MB
    ushort* xrb   = xlb + (size_t)N_NODES * HC;             // 12.8 MB
    float*  gsum   = (float*)(xrb + (size_t)N_NODES * HC);  // 512 B
    float*  gsumsq = gsum + HC;                             // 512 B
    int*    deg16  = (int*)(gsumsq + HC);                   // 3.2 MB
    ushort* csrp = (ushort*)(deg16 + (size_t)N_NODES * DEG_STRIDE);  // 6.4 MB
    ushort* wtl  = csrp + (size_t)N_NODES * CAP;            // 32 KB
    ushort* wtr  = wtl + 16384;                             // 32 KB

    hipLaunchKernelGGL(init_k, dim3(196), dim3(256), 0, stream,
                       Wl, Wr, wtl, wtr, deg16, csrp, gsum);
    hipLaunchKernelGGL(eg_k, dim3(FUSED_GRID), dim3(512), 0, stream,
                       ei, deg16, csrp, x, wtl, wtr, xlb, xrb);
    hipLaunchKernelGGL(attn_k, dim3(N_NODES / 4), dim3(256), 0, stream,
                       xlb, xrb, deg16, csrp, att, bias, out);
    hipLaunchKernelGGL(stats_k, dim3(ST_BLOCKS), dim3(512), 0, stream,
                       out, gsum, gsumsq);
    hipLaunchKernelGGL(norm_k, dim3(NM_BLOCKS), dim3(256), 0, stream,
                       out, gsum, gsumsq, gw, gb, gms);
}

// Round 9
// 207.003 us; speedup vs baseline: 1.1690x; 1.1690x over previous
//
#include <hip/hip_runtime.h>
#include <hip/hip_bf16.h>
#include <math.h>

#define N_NODES 50000
#define F_IN 128
#define HC 128
#define N_EDGES 800000
#define E_HALF_R (N_EDGES / 2)      // 400000 (real edges only; self-loops via init_k)
#define NEG_SLOPE 0.2f
#define GN_EPS 1e-5f
#define DEG_STRIDE 16               // one counter per 64B line
#define CAP 64                      // padded CSR capacity (max deg ~35 + self)
#define GB ((N_NODES + 127) / 128)  // 391 gemm-role blocks
#define EBR ((E_HALF_R + 511) / 512) // 782 edge-role blocks (2 edges/thread)
#define FUSED_GRID (GB + EBR)       // 1173 == 3*GB exactly
#define ST_BLOCKS 256               // x16 row-lanes = 4096 slots, 13 unrolled steps
#define ST_ITERS 13                 // 4096*13 = 53248 >= 50000
#define NM_BLOCKS 1024              // x8 row-lanes = 8192 slots, 7 unrolled steps
#define NM_ITERS 7                  // 8192*7 = 57344 >= 50000

typedef __attribute__((ext_vector_type(8))) short short8;
typedef __attribute__((ext_vector_type(4))) float floatx4;

__device__ inline ushort f2bf(float f) {
    unsigned u = __float_as_uint(f);
    u += 0x7FFF + ((u >> 16) & 1);   // RNE (inputs are finite/bounded)
    return (ushort)(u >> 16);
}

// ---------------------------------------------------------------- init: W transpose + self-loop CSR slot0 + stats zero
__global__ __launch_bounds__(256) void init_k(const float* __restrict__ Wl,
                                              const float* __restrict__ Wr,
                                              ushort* __restrict__ wtl,
                                              ushort* __restrict__ wtr,
                                              int* __restrict__ deg16,
                                              ushort* __restrict__ csrp,
                                              float* __restrict__ gsum) {
    int gid = blockIdx.x * 256 + threadIdx.x;
    if (gid < 16384) {               // W is [k][n]; write [n][k] bf16
        int k = gid >> 7, n = gid & 127;
        wtl[n * 128 + k] = f2bf(Wl[gid]);
        wtr[n * 128 + k] = f2bf(Wr[gid]);
    }
    if (gid < 256) gsum[gid] = 0.f;  // gsum[128] + gsumsq[128] contiguous
    if (gid < N_NODES) {
        deg16[gid * DEG_STRIDE] = 1;         // slot 0 taken by self-loop
        csrp[(size_t)gid * CAP] = (ushort)gid;
    }
}

// ---------------------------------------------------------------- fused edge-scatter + dual MFMA GEMM
// Role-split blocks: bi%3==1 -> GEMM (391), else edge (782). Edge blocks are
// atomic-latency-bound (15.1 G returning-atomics/s fabric ceiling, invariant
// R0-R6 across occupancy 30-57%); GEMM blocks backfill the idle pipes.
__global__ __launch_bounds__(512) void eg_k(const int* __restrict__ ei,
                                            int* __restrict__ deg16,
                                            ushort* __restrict__ csrp,
                                            const float* __restrict__ x,
                                            const ushort* __restrict__ wtl,
                                            const ushort* __restrict__ wtr,
                                            ushort* __restrict__ xlb,
                                            ushort* __restrict__ xrb) {
    __shared__ ushort Wt[2][128][136];
    const int bi = blockIdx.x;
    const int tid = threadIdx.x;
    const bool isG = (bi % 3 == 1);

    if (!isG) {
        // ---- edge role: 2 independent real edges per thread (split halves) ----
        const int eb = bi - (bi + 1) / 3;
        int gid = eb * 512 + tid;
        if (gid >= E_HALF_R) return;
        {   // edge A: [0, 400000)
            int src = ei[gid], dst = ei[N_EDGES + gid];
            int r = atomicAdd(&deg16[dst * DEG_STRIDE], 1);
            if (r < CAP) csrp[(size_t)dst * CAP + r] = (ushort)src;
        }
        {   // edge B: [400000, 800000)
            int e = gid + E_HALF_R;
            int src = ei[e], dst = ei[N_EDGES + e];
            int r = atomicAdd(&deg16[dst * DEG_STRIDE], 1);
            if (r < CAP) csrp[(size_t)dst * CAP + r] = (ushort)src;
        }
        return;
    }

    // ---- gemm role: 8 waves, 128 rows/block, LDS-staged both W ----
    const int gb = bi / 3;
#pragma unroll
    for (int i = 0; i < 4; ++i) {
        int idx = i * 512 + tid;
        int n = idx >> 4, k8 = (idx & 15) * 8;
        *(int4*)&Wt[0][n][k8] = *(const int4*)(wtl + n * 128 + k8);
        *(int4*)&Wt[1][n][k8] = *(const int4*)(wtr + n * 128 + k8);
    }
    __syncthreads();

    const int w = tid >> 6, lane = tid & 63;
    const int quad = lane >> 4, l16 = lane & 15;
    const int rbase = gb * 128 + w * 16;
    const int grow = rbase + l16;
    const float* ap = x + (size_t)(grow < N_NODES ? grow : (N_NODES - 1)) * F_IN + quad * 8;

    floatx4 accL[8], accR[8];
#pragma unroll
    for (int nt = 0; nt < 8; ++nt) {
        accL[nt] = (floatx4){0.f, 0.f, 0.f, 0.f};
        accR[nt] = (floatx4){0.f, 0.f, 0.f, 0.f};
    }

#pragma unroll
    for (int ks = 0; ks < 4; ++ks) {
        float4 a0 = *(const float4*)(ap + ks * 32 + 0);
        float4 a1 = *(const float4*)(ap + ks * 32 + 4);
        short8 af;
        af[0] = (short)f2bf(a0.x); af[1] = (short)f2bf(a0.y);
        af[2] = (short)f2bf(a0.z); af[3] = (short)f2bf(a0.w);
        af[4] = (short)f2bf(a1.x); af[5] = (short)f2bf(a1.y);
        af[6] = (short)f2bf(a1.z); af[7] = (short)f2bf(a1.w);
#pragma unroll
        for (int nt = 0; nt < 8; ++nt) {
            short8 bfl = *(const short8*)&Wt[0][nt * 16 + l16][ks * 32 + quad * 8];
            short8 bfr = *(const short8*)&Wt[1][nt * 16 + l16][ks * 32 + quad * 8];
            accL[nt] = __builtin_amdgcn_mfma_f32_16x16x32_bf16(af, bfl, accL[nt], 0, 0, 0);
            accR[nt] = __builtin_amdgcn_mfma_f32_16x16x32_bf16(af, bfr, accR[nt], 0, 0, 0);
        }
    }
    // C/D: row = rbase + quad*4 + r, col = nt*16 + l16
#pragma unroll
    for (int r = 0; r < 4; ++r) {
        int gro = rbase + quad * 4 + r;
        if (gro < N_NODES) {
            ushort* opl = xlb + (size_t)gro * HC + l16;
            ushort* opr = xrb + (size_t)gro * HC + l16;
#pragma unroll
            for (int nt = 0; nt < 8; ++nt) {
                opl[nt * 16] = f2bf(accL[nt][r]);
                opr[nt * 16] = f2bf(accR[nt][r]);
            }
        }
    }
}

// ---------------------------------------------------------------- fused attention — full-MLP, work-proportional
// One wave per dst. nk is wave-uniform -> per-step guards are uniform scalar
// branches (cheap). All of the row's gathers are issued before any
// consumption (up to 8 in flight; second batch of 8 for the rare nk>32).
// EDGE_STEP count/order/masks identical to the proven R6 loop ->
// bitwise-identical accumulation. R8's bucket quantization (4/8/16 steps)
// over-executed EDGE_STEPs by ~60% at deg~17 -> VALUBusy 51%, 76us; this
// form has R6's work with 4x the memory-level parallelism.
__global__ __launch_bounds__(256) void attn_k(const ushort* __restrict__ xlb,
                                              const ushort* __restrict__ xrb,
                                              const int* __restrict__ deg16,
                                              const ushort* __restrict__ csrp,
                                              const float* __restrict__ att,
                                              const float* __restrict__ bias,
                                              float* __restrict__ out) {
    const int wid = threadIdx.x >> 6, lane = threadIdx.x & 63;
    const int dst = blockIdx.x * 4 + wid;
    if (dst >= N_NODES) return;
    const int e = lane >> 4, s = lane & 15;
    float xrv[8], av[8];
    {
        int4 xv = *(const int4*)(xrb + (size_t)dst * HC + s * 8);
        xrv[0] = __uint_as_float(((unsigned)xv.x) << 16);
        xrv[1] = __uint_as_float(((unsigned)xv.x) & 0xffff0000u);
        xrv[2] = __uint_as_float(((unsigned)xv.y) << 16);
        xrv[3] = __uint_as_float(((unsigned)xv.y) & 0xffff0000u);
        xrv[4] = __uint_as_float(((unsigned)xv.z) << 16);
        xrv[5] = __uint_as_float(((unsigned)xv.z) & 0xffff0000u);
        xrv[6] = __uint_as_float(((unsigned)xv.w) << 16);
        xrv[7] = __uint_as_float(((unsigned)xv.w) & 0xffff0000u);
        float4 a0 = *(const float4*)(att + s * 8);
        float4 a1 = *(const float4*)(att + s * 8 + 4);
        av[0] = a0.x; av[1] = a0.y; av[2] = a0.z; av[3] = a0.w;
        av[4] = a1.x; av[5] = a1.y; av[6] = a1.z; av[7] = a1.w;
    }
    float l = 0.f;
    float acc[8] = {0.f, 0.f, 0.f, 0.f, 0.f, 0.f, 0.f, 0.f};
    const int nk = min(deg16[dst * DEG_STRIDE], CAP);
    const int sv = (int)csrp[(size_t)dst * CAP + lane];   // lanes >= nk never selected

#define EDGE_STEP(rv, valid)                                                   \
    {                                                                          \
        float f0 = __uint_as_float(((unsigned)(rv).x) << 16);                  \
        float f1 = __uint_as_float(((unsigned)(rv).x) & 0xffff0000u);          \
        float f2 = __uint_as_float(((unsigned)(rv).y) << 16);                  \
        float f3 = __uint_as_float(((unsigned)(rv).y) & 0xffff0000u);          \
        float f4 = __uint_as_float(((unsigned)(rv).z) << 16);                  \
        float f5 = __uint_as_float(((unsigned)(rv).z) & 0xffff0000u);          \
        float f6 = __uint_as_float(((unsigned)(rv).w) << 16);                  \
        float f7 = __uint_as_float(((unsigned)(rv).w) & 0xffff0000u);          \
        float t_, part_;                                                       \
        t_ = f0 + xrv[0]; t_ = t_ > 0.f ? t_ : NEG_SLOPE * t_; part_ = av[0] * t_;  \
        t_ = f1 + xrv[1]; t_ = t_ > 0.f ? t_ : NEG_SLOPE * t_; part_ += av[1] * t_; \
        t_ = f2 + xrv[2]; t_ = t_ > 0.f ? t_ : NEG_SLOPE * t_; part_ += av[2] * t_; \
        t_ = f3 + xrv[3]; t_ = t_ > 0.f ? t_ : NEG_SLOPE * t_; part_ += av[3] * t_; \
        t_ = f4 + xrv[4]; t_ = t_ > 0.f ? t_ : NEG_SLOPE * t_; part_ += av[4] * t_; \
        t_ = f5 + xrv[5]; t_ = t_ > 0.f ? t_ : NEG_SLOPE * t_; part_ += av[5] * t_; \
        t_ = f6 + xrv[6]; t_ = t_ > 0.f ? t_ : NEG_SLOPE * t_; part_ += av[6] * t_; \
        t_ = f7 + xrv[7]; t_ = t_ > 0.f ? t_ : NEG_SLOPE * t_; part_ += av[7] * t_; \
        part_ += __shfl_xor(part_, 1, 4);                                      \
        part_ += __shfl_xor(part_, 2, 4);                                      \
        float p = (valid) ? __expf(part_) : 0.f;                               \
        l += p;                                                                \
        acc[0] += p * f0; acc[1] += p * f1; acc[2] += p * f2; acc[3] += p * f3;\
        acc[4] += p * f4; acc[5] += p * f5; acc[6] += p * f6; acc[7] += p * f7;\
    }

#define GATHER(dst_rv, step)                                                   \
    {                                                                          \
        int idx_ = (step) * 4 + e;                                             \
        int ii_ = idx_ < nk ? idx_ : 0;                                        \
        int sr_ = __shfl(sv, ii_, 64);                                         \
        (dst_rv) = *(const int4*)(xlb + (size_t)sr_ * HC + s * 8);             \
    }

    const int nsteps = (nk + 3) >> 2;   // 1..16 steps of 4 edges (nk>=1)
    int4 rv[8];
    // ---- batch 1: steps 0..min(nsteps,8)-1 — all gathers in flight first
    GATHER(rv[0], 0)
    if (nsteps > 1) GATHER(rv[1], 1)
    if (nsteps > 2) GATHER(rv[2], 2)
    if (nsteps > 3) GATHER(rv[3], 3)
    if (nsteps > 4) GATHER(rv[4], 4)
    if (nsteps > 5) GATHER(rv[5], 5)
    if (nsteps > 6) GATHER(rv[6], 6)
    if (nsteps > 7) GATHER(rv[7], 7)
    EDGE_STEP(rv[0], (0 + e) < nk)
    if (nsteps > 1) EDGE_STEP(rv[1], (4 + e) < nk)
    if (nsteps > 2) EDGE_STEP(rv[2], (8 + e) < nk)
    if (nsteps > 3) EDGE_STEP(rv[3], (12 + e) < nk)
    if (nsteps > 4) EDGE_STEP(rv[4], (16 + e) < nk)
    if (nsteps > 5) EDGE_STEP(rv[5], (20 + e) < nk)
    if (nsteps > 6) EDGE_STEP(rv[6], (24 + e) < nk)
    if (nsteps > 7) EDGE_STEP(rv[7], (28 + e) < nk)
    if (nsteps > 8) {                   // ---- batch 2: rare (nk > 32)
        GATHER(rv[0], 8)
        if (nsteps > 9)  GATHER(rv[1], 9)
        if (nsteps > 10) GATHER(rv[2], 10)
        if (nsteps > 11) GATHER(rv[3], 11)
        if (nsteps > 12) GATHER(rv[4], 12)
        if (nsteps > 13) GATHER(rv[5], 13)
        if (nsteps > 14) GATHER(rv[6], 14)
        if (nsteps > 15) GATHER(rv[7], 15)
        EDGE_STEP(rv[0], (32 + e) < nk)
        if (nsteps > 9)  EDGE_STEP(rv[1], (36 + e) < nk)
        if (nsteps > 10) EDGE_STEP(rv[2], (40 + e) < nk)
        if (nsteps > 11) EDGE_STEP(rv[3], (44 + e) < nk)
        if (nsteps > 12) EDGE_STEP(rv[4], (48 + e) < nk)
        if (nsteps > 13) EDGE_STEP(rv[5], (52 + e) < nk)
        if (nsteps > 14) EDGE_STEP(rv[6], (56 + e) < nk)
        if (nsteps > 15) EDGE_STEP(rv[7], (60 + e) < nk)
    }
#undef GATHER
#undef EDGE_STEP

    l += __shfl_xor(l, 16, 64);
    l += __shfl_xor(l, 32, 64);
#pragma unroll
    for (int c = 0; c < 8; ++c) {
        acc[c] += __shfl_xor(acc[c], 16, 64);
        acc[c] += __shfl_xor(acc[c], 32, 64);
    }
    if (e == 0) {
        float inv = 1.0f / l;
        float4 b0 = *(const float4*)(bias + s * 8);
        float4 b1 = *(const float4*)(bias + s * 8 + 4);
        float4 o0 = make_float4(acc[0] * inv + b0.x, acc[1] * inv + b0.y,
                                acc[2] * inv + b0.z, acc[3] * inv + b0.w);
        float4 o1 = make_float4(acc[4] * inv + b1.x, acc[5] * inv + b1.y,
                                acc[6] * inv + b1.z, acc[7] * inv + b1.w);
        *(float4*)(out + (size_t)dst * HC + s * 8)     = o0;
        *(float4*)(out + (size_t)dst * HC + s * 8 + 4) = o1;
    }
}

// ---------------------------------------------------------------- per-feature sum/sumsq (13 independent loads in flight)
__global__ __launch_bounds__(512) void stats_k(const float* __restrict__ out,
                                               float* __restrict__ gsum,
                                               float* __restrict__ gsumsq) {
    const int t = threadIdx.x;
    const int fg = t & 31;          // features 4fg..4fg+3
    const int rl = t >> 5;          // 0..15 row-lane
    const int rbase = blockIdx.x * 16 + rl;
    float4 v[ST_ITERS];
#pragma unroll
    for (int i = 0; i < ST_ITERS; ++i) {
        int r = rbase + i * (ST_BLOCKS * 16);
        int rr = r < N_NODES ? r : 0;            // clamp addr, mask below
        v[i] = *(const float4*)(out + (size_t)rr * HC + fg * 4);
    }
    float4 s  = make_float4(0.f, 0.f, 0.f, 0.f);
    float4 s2 = make_float4(0.f, 0.f, 0.f, 0.f);
#pragma unroll
    for (int i = 0; i < ST_ITERS; ++i) {
        int r = rbase + i * (ST_BLOCKS * 16);
        if (r < N_NODES) {
            s.x += v[i].x; s.y += v[i].y; s.z += v[i].z; s.w += v[i].w;
            s2.x += v[i].x * v[i].x; s2.y += v[i].y * v[i].y;
            s2.z += v[i].z * v[i].z; s2.w += v[i].w * v[i].w;
        }
    }
    __shared__ float4 L1[512], L2[512];
    L1[t] = s; L2[t] = s2;
    __syncthreads();
#pragma unroll
    for (int off = 256; off >= 32; off >>= 1) {
        if (t < off) {
            float4 a = L1[t], b = L1[t + off];
            a.x += b.x; a.y += b.y; a.z += b.z; a.w += b.w; L1[t] = a;
            float4 c = L2[t], d = L2[t + off];
            c.x += d.x; c.y += d.y; c.z += d.z; c.w += d.w; L2[t] = c;
        }
        __syncthreads();
    }
    if (t < 32) {
        float4 a = L1[t], c = L2[t];
        atomicAdd(&gsum[t * 4 + 0], a.x); atomicAdd(&gsum[t * 4 + 1], a.y);
        atomicAdd(&gsum[t * 4 + 2], a.z); atomicAdd(&gsum[t * 4 + 3], a.w);
        atomicAdd(&gsumsq[t * 4 + 0], c.x); atomicAdd(&gsumsq[t * 4 + 1], c.y);
        atomicAdd(&gsumsq[t * 4 + 2], c.z); atomicAdd(&gsumsq[t * 4 + 3], c.w);
    }
}

// ---------------------------------------------------------------- GraphNorm finalize (7 independent loads in flight)
__global__ __launch_bounds__(256) void norm_k(float* __restrict__ out,
                                              const float* __restrict__ gsum,
                                              const float* __restrict__ gsumsq,
                                              const float* __restrict__ gw,
                                              const float* __restrict__ gb,
                                              const float* __restrict__ gms) {
    const int t = threadIdx.x;
    const int fg = t & 31;          // features 4fg..4fg+3
    const int rl = t >> 5;          // 0..7
    const int rbase = blockIdx.x * 8 + rl;
    float4 v[NM_ITERS];
#pragma unroll
    for (int i = 0; i < NM_ITERS; ++i) {
        int r = rbase + i * (NM_BLOCKS * 8);
        int rr = r < N_NODES ? r : 0;
        v[i] = *(const float4*)(out + (size_t)rr * HC + fg * 4);
    }
    const float invN = 1.0f / (float)N_NODES;
    float4 sm = *(const float4*)(gsum + fg * 4);
    float4 sq = *(const float4*)(gsumsq + fg * 4);
    float4 gv = *(const float4*)(gms + fg * 4);
    float4 wv = *(const float4*)(gw + fg * 4);
    float4 bv = *(const float4*)(gb + fg * 4);
    float4 a, b;
#define MKAB(c)                                                                \
    {                                                                          \
        float mean = sm.c * invN, msq = sq.c * invN, g = gv.c;                 \
        float var = msq - 2.f * g * mean * mean + g * g * mean * mean;         \
        a.c = wv.c * rsqrtf(var + GN_EPS);                                     \
        b.c = bv.c - a.c * g * mean;                                           \
    }
    MKAB(x) MKAB(y) MKAB(z) MKAB(w)
#undef MKAB
#pragma unroll
    for (int i = 0; i < NM_ITERS; ++i) {
        int r = rbase + i * (NM_BLOCKS * 8);
        if (r < N_NODES) {
            float4 w = v[i];
            w.x = a.x * w.x + b.x; w.y = a.y * w.y + b.y;
            w.z = a.z * w.z + b.z; w.w = a.w * w.w + b.w;
            *(float4*)(out + (size_t)r * HC + fg * 4) = w;
        }
    }
}

// ---------------------------------------------------------------- launch
extern "C" void kernel_launch(void* const* d_in, const int* in_sizes, int n_in,
                              void* d_out, int out_size, void* d_ws, size_t ws_size,
                              hipStream_t stream) {
    const float* x    = (const float*)d_in[0];
    const int*   ei   = (const int*)d_in[1];
    const float* Wl   = (const float*)d_in[2];
    const float* Wr   = (const float*)d_in[3];
    const float* att  = (const float*)d_in[4];
    const float* bias = (const float*)d_in[5];
    const float* gw   = (const float*)d_in[6];
    const float* gb   = (const float*)d_in[7];
    const float* gms  = (const float*)d_in[8];
    float* out = (float*)d_out;

    // workspace layout (~35.3 MB), all segments 16B-aligned
    ushort* xlb   = (ushort*)d_ws;                          // 12.8 MB
    ushort* xrb   = xlb + (size_t)N_NODES * HC;             // 12.8 MB
    float*  gsum   = (float*)(xrb + (size_t)N_NODES * HC);  // 512 B
    float*  gsumsq = gsum + HC;                             // 512 B
    int*    deg16  = (int*)(gsumsq + HC);                   // 3.2 MB
    ushort* csrp = (ushort*)(deg16 + (size_t)N_NODES * DEG_STRIDE);  // 6.4 MB
    ushort* wtl  = csrp + (size_t)N_NODES * CAP;            // 32 KB
    ushort* wtr  = wtl + 16384;                             // 32 KB

    hipLaunchKernelGGL(init_k, dim3(196), dim3(256), 0, stream,
                       Wl, Wr, wtl, wtr, deg16, csrp, gsum);
    hipLaunchKernelGGL(eg_k, dim3(FUSED_GRID), dim3(512), 0, stream,
                       ei, deg16, csrp, x, wtl, wtr, xlb, xrb);
    hipLaunchKernelGGL(attn_k, dim3(N_NODES / 4), dim3(256), 0, stream,
                       xlb, xrb, deg16, csrp, att, bias, out);
    hipLaunchKernelGGL(stats_k, dim3(ST_BLOCKS), dim3(512), 0, stream,
                       out, gsum, gsumsq);
    hipLaunchKernelGGL(norm_k, dim3(NM_BLOCKS), dim3(256), 0, stream,
                       out, gsum, gsumsq, gw, gb, gms);
}